// Round 11
// baseline (61.616 us; speedup 1.0000x reference)
//
#include <hip/hip_runtime.h>
#include <hip/hip_bf16.h>
#include <math.h>

#define PSZ   147456           // pixels per sample (384*384)
#define NTOT  1179648          // 8 * PSZ
#define WW    384
#define HH    384
#define NIMG  8
#define NBINH 2048             // histogram bins, width 1/256, covers e in (0,8)
#define INF2F 294913.0f        // H*H + W*W + 1
#define GV2   1152             // k_fused blocks (4 px per thread)
#define EBLK  768              // k_edth blocks (4 rows each)

// ---- exact, contraction-proof helpers ----
static __device__ __forceinline__ float errval(float x, float z) {
    float s = __fsub_rn(__fmul_rn(2.0f, z), 1.0f);   // exactly +-1
    return __fsub_rn(1.0f, __fmul_rn(x, s));
}
static __device__ __forceinline__ int binof(float e) {
    int b = (int)(__fmul_rn(e, 256.0f));
    return b > (NBINH - 1) ? (NBINH - 1) : b;
}
static __device__ __forceinline__ float d2f(int d) {  // exact: |d|<=600 -> d*d < 2^24
    return (float)(d * d);
}

// nearest set-bit distance from column p for mask m (fg) AND ~m (bg), one pass.
struct DPair { int df, db; };
static __device__ __forceinline__ DPair ndist2(const unsigned long long* __restrict__ m, int p) {
    const int BIG = 1 << 20;
    int q = p >> 6, b = p & 63;
    int df = BIG, db = BIG;
    {   // right scan (bits >= p, incl. self)
        unsigned long long w = m[q];
        unsigned long long tf = w >> b;
        unsigned long long tb = (~w) >> b;
        if (tf) df = __builtin_ctzll(tf);
        if (tb) db = __builtin_ctzll(tb);
        for (int u = q + 1; (df == BIG || db == BIG) && u < 6; ++u) {
            w = m[u];
            if (df == BIG && w)  df = u * 64 + __builtin_ctzll(w)  - p;
            if (db == BIG && ~w) db = u * 64 + __builtin_ctzll(~w) - p;
        }
    }
    {   // left scan (bits <= p, incl. self)
        unsigned long long w = m[q];
        unsigned long long tf = w << (63 - b);
        unsigned long long tb = (~w) << (63 - b);
        int lf = BIG, lb = BIG;
        if (tf) lf = __builtin_clzll(tf);
        if (tb) lb = __builtin_clzll(tb);
        for (int u = q - 1; (lf == BIG || lb == BIG) && u >= 0; --u) {
            w = m[u];
            if (lf == BIG && w)  lf = p - (u * 64 + 63 - __builtin_clzll(w));
            if (lb == BIG && ~w) lb = p - (u * 64 + 63 - __builtin_clzll(~w));
        }
        if (lf < df) df = lf;
        if (lb < db) db = lb;
    }
    DPair r;
    r.df = (df > 600) ? 600 : df;
    r.db = (db > 600) ? 600 : db;
    return r;
}

// ---- K0: zero the histogram + maxabs (replaces pathologically slow runtime memset) ----
__global__ __launch_bounds__(256) void k_zero(unsigned long long* __restrict__ hist,
                                              unsigned int* __restrict__ maxabsBits) {
    int idx = blockIdx.x * 256 + threadIdx.x;        // grid*block == NIMG*NBINH*2 exactly
    hist[idx] = 0ull;
    if (idx < 16) maxabsBits[idx] = 0u;
}

// ---- K1: horizontal EDT (ballot masks -> packed u16 dists) + LDS histogram ----
// XCD-partitioned: img = blockIdx % 8 -> each image stays on one XCD's L2.
__global__ __launch_bounds__(256) void k_edth(const float* __restrict__ tgt,
                                              const float* __restrict__ pred,
                                              unsigned int* __restrict__ g2,
                                              unsigned long long* __restrict__ hist) {
    __shared__ unsigned long long h[NBINH * 2];      // 32 KB
    for (int q = threadIdx.x; q < NBINH * 2; q += 256) h[q] = 0ull;
    __syncthreads();
    int img = blockIdx.x & 7;
    int bb  = blockIdx.x >> 3;                       // 0..95
    int row = img * HH + bb * 4 + (threadIdx.x >> 6);
    int l = threadIdx.x & 63;
    const float* tr = tgt  + (size_t)row * WW;
    const float* pr = pred + (size_t)row * WW;
    float zv[6], xv[6];
    unsigned long long mf[6];
#pragma unroll
    for (int c = 0; c < 6; ++c) { zv[c] = tr[c * 64 + l]; xv[c] = pr[c * 64 + l]; }
#pragma unroll
    for (int c = 0; c < 6; ++c) mf[c] = __ballot(zv[c] > 0.5f);   // wave-uniform row mask
    size_t ob = (size_t)row * WW;
#pragma unroll
    for (int c = 0; c < 6; ++c) {
        int p = c * 64 + l;
        DPair d = ndist2(mf, p);
        g2[ob + p] = (unsigned int)d.df | ((unsigned int)d.db << 16);
        float e = errval(xv[c], zv[c]);
        if (e > 0.0f) {
            int lab = (zv[c] > 0.5f) ? 1 : 0;
            unsigned long long add = (1ull << 46) |
                (unsigned long long)__fmul_rn(e, 16777216.0f);
            atomicAdd(&h[(binof(e) << 1) + lab], add);
        }
    }
    __syncthreads();
    unsigned long long* gh = hist + ((size_t)img * NBINH << 1);
    for (int q = threadIdx.x; q < NBINH * 2; q += 256) {
        unsigned long long v = h[q];
        if (v) atomicAdd(&gh[q], v);                 // integer add: deterministic
    }
}

// ---- K2: fused vertical EDT (24-row shared window, 4 px/thread) + elementwise ----
__global__ __launch_bounds__(256) void k_fused(const float* __restrict__ pred,
                                               const float* __restrict__ tgt,
                                               const unsigned int* __restrict__ g2,
                                               float* __restrict__ pB, float* __restrict__ pP,
                                               float* __restrict__ pPT, float* __restrict__ pBnd,
                                               unsigned int* __restrict__ pPc,
                                               unsigned int* __restrict__ maxabsBits) {
    int t = threadIdx.x;
    int img = blockIdx.x & 7;                        // XCD partition: image <-> XCD
    int bb  = blockIdx.x >> 3;                       // 0..143
    int v   = bb * 256 + t;                          // 0..36863
    int j   = v % WW;
    int i0  = (v / WW) * 4;                          // 4 consecutive rows per thread
    const unsigned int* g2i = g2 + (size_t)img * PSZ;
    // 24 independent loads cover the r<=8 window of all 4 pixels (one round trip).
    // Clamped rows only add candidates with larger r^2 -> min stays exact.
    unsigned int w[24];
#pragma unroll
    for (int k = 0; k < 24; ++k) {
        int rr = i0 - 8 + k;
        rr = rr < 0 ? 0 : (rr > HH - 1 ? HH - 1 : rr);
        w[k] = g2i[rr * WW + j];
    }
    float aF[4], aB[4];
#pragma unroll
    for (int m = 0; m < 4; ++m) {
        float f = INF2F, g = INF2F;
#pragma unroll
        for (int k = m; k <= m + 16; ++k) {
            float r2 = d2f(k - 8 - m);
            f = fminf(f, r2 + d2f((int)(w[k] & 0xffffu)));
            g = fminf(g, r2 + d2f((int)(w[k] >> 16)));
        }
        aF[m] = f; aB[m] = g;
    }
    // straggler loop r>8 (exact; essentially never taken on this data)
#pragma unroll
    for (int m = 0; m < 4; ++m) {
        int i = i0 + m;
        for (int r = 9; r < HH; ++r) {
            float r2 = d2f(r);
            if (r2 >= fmaxf(aF[m], aB[m])) break;
            int up = i - r, dn = i + r;
            if (up >= 0) {
                unsigned int ww = g2i[up * WW + j];
                aF[m] = fminf(aF[m], r2 + d2f((int)(ww & 0xffffu)));
                aB[m] = fminf(aB[m], r2 + d2f((int)(ww >> 16)));
            }
            if (dn < HH) {
                unsigned int ww = g2i[dn * WW + j];
                aF[m] = fminf(aF[m], r2 + d2f((int)(ww & 0xffffu)));
                aB[m] = fminf(aB[m], r2 + d2f((int)(ww >> 16)));
            }
        }
    }
    // elementwise for the 4 pixels
    float vals[6] = {0.f, 0.f, 0.f, 0.f, 0.f, 0.f};
#pragma unroll
    for (int m = 0; m < 4; ++m) {
        int n = img * PSZ + (i0 + m) * WW + j;
        float x = pred[n], z = tgt[n];
        bool lab = z > 0.5f;
        float dv = lab ? -sqrtf(fminf(aB[m], INF2F)) : sqrtf(fminf(aF[m], INF2F));
        float bce = fmaxf(x, 0.0f) - x * z + log1pf(expf(-fabsf(x)));
        float p = 1.0f / (1.0f + expf(-x));
        vals[0] += bce; vals[1] += p;
        vals[2] += lab ? p : 0.0f;
        vals[3] += p * dv;
        vals[4] += lab ? 1.0f : 0.0f;
        vals[5] = fmaxf(vals[5], fabsf(dv));
    }
    // wave butterfly reductions (fixed order -> deterministic)
#pragma unroll
    for (int k = 0; k < 5; ++k)
#pragma unroll
        for (int off = 32; off; off >>= 1) vals[k] += __shfl_xor(vals[k], off);
#pragma unroll
    for (int off = 32; off; off >>= 1) vals[5] = fmaxf(vals[5], __shfl_xor(vals[5], off));
    __shared__ float sw[4][6];
    int wv = t >> 6, lnn = t & 63;
    if (lnn == 0) {
#pragma unroll
        for (int k = 0; k < 6; ++k) sw[wv][k] = vals[k];
    }
    __syncthreads();
    if (t < 6) {
        int k = t;
        if (k == 5) {
            float a = fmaxf(fmaxf(sw[0][5], sw[1][5]), fmaxf(sw[2][5], sw[3][5]));
            atomicMax(maxabsBits, __float_as_uint(a));
        } else {
            float a = sw[0][k] + sw[1][k] + sw[2][k] + sw[3][k];
            if (k == 0) pB[blockIdx.x] = a;
            else if (k == 1) pP[blockIdx.x] = a;
            else if (k == 2) pPT[blockIdx.x] = a;
            else if (k == 3) pBnd[blockIdx.x] = a;
            else pPc[blockIdx.x] = (unsigned int)(a + 0.5f);
        }
    }
}

// ---- K3: per-sample Lovasz scan + partial-sum reduction (8 blocks, 1/CU) ----
__global__ __launch_bounds__(256) void k_scanlov(const unsigned long long* __restrict__ hist,
                                                 const unsigned int* __restrict__ pPc,
                                                 const float* __restrict__ pB, const float* __restrict__ pP,
                                                 const float* __restrict__ pPT, const float* __restrict__ pBnd,
                                                 double* __restrict__ sums,   // [8][5]: B,P,PT,Bnd,Lov
                                                 unsigned int* __restrict__ Pfin) {
    int b = blockIdx.x, t = threadIdx.x;
    __shared__ double dred[256];
    __shared__ unsigned int ured[256];
    // per-sample reduction of the float partials (entries q = b + 8k, k<144)
    double mv[4] = {0.0, 0.0, 0.0, 0.0};
    unsigned int mc = 0;
    if (t < 144) {
        int q = b + 8 * t;
        mv[0] = (double)pB[q]; mv[1] = (double)pP[q];
        mv[2] = (double)pPT[q]; mv[3] = (double)pBnd[q];
        mc = pPc[q];
    }
    ured[t] = mc; __syncthreads();
    for (int s = 128; s > 0; s >>= 1) { if (t < s) ured[t] += ured[t + s]; __syncthreads(); }
    unsigned int Pfull = ured[0];
    __syncthreads();
#pragma unroll
    for (int a = 0; a < 4; ++a) {
        dred[t] = mv[a]; __syncthreads();
        for (int s = 128; s > 0; s >>= 1) { if (t < s) dred[t] += dred[t + s]; __syncthreads(); }
        if (t == 0) sums[b * 5 + a] = dred[0];
        __syncthreads();
    }
    // bin-count prefix scan: 8 bins/thread, shfl wave-scan + cross-wave bases
    const unsigned long long* hc = hist + ((size_t)b * NBINH << 1);
    int m0 = t * 8;
    unsigned int ln = 0, lp = 0;
    unsigned int hcn[8], hcp[8];
    unsigned long long hsn[8], hsp[8];
#pragma unroll
    for (int k = 0; k < 8; ++k) {
        unsigned long long vn = hc[2 * (m0 + k)], vp = hc[2 * (m0 + k) + 1];
        hcn[k] = (unsigned int)(vn >> 46); hcp[k] = (unsigned int)(vp >> 46);
        hsn[k] = vn & ((1ull << 46) - 1);  hsp[k] = vp & ((1ull << 46) - 1);
        ln += hcn[k]; lp += hcp[k];
    }
    int lane = t & 63, wv = t >> 6;
    unsigned int sln = ln, slp = lp;
#pragma unroll
    for (int off = 1; off < 64; off <<= 1) {
        unsigned int an = __shfl_up(sln, off);
        unsigned int ap = __shfl_up(slp, off);
        if (lane >= off) { sln += an; slp += ap; }
    }
    __shared__ unsigned int wN[4], wP[4];
    if (lane == 63) { wN[wv] = sln; wP[wv] = slp; }
    __syncthreads();
    unsigned int baseN = 0, baseP = 0, totN = 0, totP = 0;
#pragma unroll
    for (int q = 0; q < 4; ++q) {
        if (q < wv) { baseN += wN[q]; baseP += wP[q]; }
        totN += wN[q]; totP += wP[q];
    }
    unsigned int runN = baseN + sln - ln;            // bins < m0
    unsigned int runP = baseP + slp - lp;
    // Lovasz closed form, 2 f64 divisions per nonempty bin
    const double EPS = 1e-7;
    const double SCL = 1.0 / 16777216.0;
    double P = (double)Pfull;
    double l = 0.0;
#pragma unroll
    for (int k = 0; k < 8; ++k) {
        unsigned int hn = hcn[k], hp = hcp[k];
        if (hn | hp) {
            double negAbove = (double)(totN - runN - hn);   // negatives in higher bins
            double D0 = P + negAbove + EPS;
            if (hp) l += ((double)hsp[k] * SCL) / D0;       // bin positives share denom
            if (hn) {
                double pAbove = (double)(totP - runP);      // positives ranked above group
                double D1 = D0 + (double)hn;
                // (P-pAbove)*(sn/hn)*(1/D0-1/D1) == (P-pAbove)*sn/(D0*D1)
                l += (P - pAbove) * ((double)hsn[k] * SCL) / (D0 * D1);
            }
            runN += hn; runP += hp;
        }
    }
    dred[t] = l; __syncthreads();
    for (int s = 128; s > 0; s >>= 1) { if (t < s) dred[t] += dred[t + s]; __syncthreads(); }
    if (t == 0) { sums[b * 5 + 4] = dred[0]; Pfin[b] = Pfull; }
}

// ---- K4: final combine (tiny, deterministic) ----
__global__ __launch_bounds__(64) void k_final(const double* __restrict__ sums,
                                              const unsigned int* __restrict__ Pfin,
                                              const unsigned int* __restrict__ maxabsBits,
                                              float* __restrict__ out) {
    if (threadIdx.x == 0) {
        double sumBCE = 0, sumP = 0, sumPT = 0, sumBD = 0, sumLV = 0, tsum = 0;
        for (int b = 0; b < NIMG; ++b) {
            sumBCE += sums[b * 5 + 0];
            sumP   += sums[b * 5 + 1];
            sumPT  += sums[b * 5 + 2];
            sumBD  += sums[b * 5 + 3];
            sumLV  += sums[b * 5 + 4];
            tsum   += (double)Pfin[b];
        }
        double bce = sumBCE / (double)NTOT;
        double dice = 1.0 - (2.0 * sumPT + 1.0) / (sumP + tsum + 1.0);
        float ma = __uint_as_float(maxabsBits[0]);
        double bnd = sumBD / (double)NTOT;
        if (ma > 0.0f) bnd = bnd / (double)ma;
        double lov = sumLV / (double)NIMG;
        double loss = 0.3 * bce + 0.3 * dice + 0.2 * bnd + 0.2 * lov;
        if (loss < 0.0) loss = 0.0;
        if (loss > 100.0) loss = 100.0;
        out[0] = (float)loss;
    }
}

extern "C" void kernel_launch(void* const* d_in, const int* in_sizes, int n_in,
                              void* d_out, int out_size, void* d_ws, size_t ws_size,
                              hipStream_t stream) {
    const float* pred = (const float*)d_in[0];
    const float* tgt  = (const float*)d_in[1];
    char* ws = (char*)d_ws;

    size_t off = 0;
    unsigned long long* hist = (unsigned long long*)(ws + off); off += (size_t)NIMG * NBINH * 2 * 8; // 256 KB
    unsigned int* maxabsBits = (unsigned int*)(ws + off); off += 64;
    off = (off + 1023) & ~(size_t)1023;
    double* sums = (double*)(ws + off); off += NIMG * 5 * 8;
    unsigned int* Pfin = (unsigned int*)(ws + off); off += NIMG * 4;
    off = (off + 63) & ~(size_t)63;
    float* pB   = (float*)(ws + off); off += (size_t)GV2 * 4;
    float* pP   = (float*)(ws + off); off += (size_t)GV2 * 4;
    float* pPT  = (float*)(ws + off); off += (size_t)GV2 * 4;
    float* pBnd = (float*)(ws + off); off += (size_t)GV2 * 4;
    unsigned int* pPc = (unsigned int*)(ws + off); off += (size_t)GV2 * 4;
    off = (off + 1023) & ~(size_t)1023;
    unsigned int* g2 = (unsigned int*)(ws + off); off += (size_t)NIMG * PSZ * 4;
    (void)off; (void)ws_size; (void)in_sizes; (void)n_in; (void)out_size;

    k_zero<<<NIMG * NBINH * 2 / 256, 256, 0, stream>>>(hist, maxabsBits);
    k_edth<<<EBLK, 256, 0, stream>>>(tgt, pred, g2, hist);
    k_fused<<<GV2, 256, 0, stream>>>(pred, tgt, g2, pB, pP, pPT, pBnd, pPc, maxabsBits);
    k_scanlov<<<NIMG, 256, 0, stream>>>(hist, pPc, pB, pP, pPT, pBnd, sums, Pfin);
    k_final<<<1, 64, 0, stream>>>(sums, Pfin, maxabsBits, (float*)d_out);
}

// Round 12
// 49.463 us; speedup vs baseline: 1.2457x; 1.2457x over previous
//
#include <hip/hip_runtime.h>
#include <hip/hip_bf16.h>
#include <math.h>

#define PSZ   147456           // pixels per sample (384*384)
#define NTOT  1179648          // 8 * PSZ
#define WW    384
#define HH    384
#define NIMG  8
#define NBINH 2048             // histogram bins, width 1/256, covers e in (0,8)
#define INF2F 294913.0f        // H*H + W*W + 1
#define GV2   1152             // k_fused blocks (4 px per thread)
#define EBLK  768              // k_edth blocks (4 rows each)
#define HPART 8                // hist partial-blocks per image

// ---- exact, contraction-proof helpers ----
static __device__ __forceinline__ float errval(float x, float z) {
    float s = __fsub_rn(__fmul_rn(2.0f, z), 1.0f);   // exactly +-1
    return __fsub_rn(1.0f, __fmul_rn(x, s));
}
static __device__ __forceinline__ int binof(float e) {
    int b = (int)(__fmul_rn(e, 256.0f));
    return b > (NBINH - 1) ? (NBINH - 1) : b;
}
static __device__ __forceinline__ float d2f(int d) {  // exact: |d|<=600 -> d*d < 2^24
    return (float)(d * d);
}

// nearest set-bit distance from column p for mask m (fg) AND ~m (bg), one pass.
struct DPair { int df, db; };
static __device__ __forceinline__ DPair ndist2(const unsigned long long* __restrict__ m, int p) {
    const int BIG = 1 << 20;
    int q = p >> 6, b = p & 63;
    int df = BIG, db = BIG;
    {   // right scan (bits >= p, incl. self)
        unsigned long long w = m[q];
        unsigned long long tf = w >> b;
        unsigned long long tb = (~w) >> b;
        if (tf) df = __builtin_ctzll(tf);
        if (tb) db = __builtin_ctzll(tb);
        for (int u = q + 1; (df == BIG || db == BIG) && u < 6; ++u) {
            w = m[u];
            if (df == BIG && w)  df = u * 64 + __builtin_ctzll(w)  - p;
            if (db == BIG && ~w) db = u * 64 + __builtin_ctzll(~w) - p;
        }
    }
    {   // left scan (bits <= p, incl. self)
        unsigned long long w = m[q];
        unsigned long long tf = w << (63 - b);
        unsigned long long tb = (~w) << (63 - b);
        int lf = BIG, lb = BIG;
        if (tf) lf = __builtin_clzll(tf);
        if (tb) lb = __builtin_clzll(tb);
        for (int u = q - 1; (lf == BIG || lb == BIG) && u >= 0; --u) {
            w = m[u];
            if (lf == BIG && w)  lf = p - (u * 64 + 63 - __builtin_clzll(w));
            if (lb == BIG && ~w) lb = p - (u * 64 + 63 - __builtin_clzll(~w));
        }
        if (lf < df) df = lf;
        if (lb < db) db = lb;
    }
    DPair r;
    r.df = (df > 600) ? 600 : df;
    r.db = (db > 600) ? 600 : db;
    return r;
}

// ---- K1: horizontal EDT only (ballot masks -> packed u16 dists); zeroes maxabs ----
// XCD-partitioned: img = blockIdx % 8 -> each image stays on one XCD's L2.
__global__ __launch_bounds__(256) void k_edth(const float* __restrict__ tgt,
                                              unsigned int* __restrict__ g2,
                                              unsigned int* __restrict__ maxabsBits) {
    if (blockIdx.x == 0 && threadIdx.x == 0) maxabsBits[0] = 0u;  // k_fused runs strictly later
    int img = blockIdx.x & 7;
    int bb  = blockIdx.x >> 3;                       // 0..95
    int row = img * HH + bb * 4 + (threadIdx.x >> 6);
    int l = threadIdx.x & 63;
    const float* tr = tgt + (size_t)row * WW;
    unsigned long long mf[6];
#pragma unroll
    for (int c = 0; c < 6; ++c)
        mf[c] = __ballot(tr[c * 64 + l] > 0.5f);     // wave-uniform row mask
    size_t ob = (size_t)row * WW;
#pragma unroll
    for (int c = 0; c < 6; ++c) {
        int p = c * 64 + l;
        DPair d = ndist2(mf, p);
        g2[ob + p] = (unsigned int)d.df | ((unsigned int)d.db << 16);
    }
}

// ---- K2: LDS histogram -> private per-block partial (NO global atomics) ----
// 64 blocks = 8 per image; partial fully overwritten -> no zero-init, deterministic.
__global__ __launch_bounds__(1024) void k_hist(const float* __restrict__ pred,
                                               const float* __restrict__ tgt,
                                               unsigned long long* __restrict__ histp) {
    __shared__ unsigned long long h[NBINH * 2];      // 32 KB
    for (int q = threadIdx.x; q < NBINH * 2; q += 1024) h[q] = 0ull;
    __syncthreads();
    int img  = blockIdx.x & 7;                       // XCD partition
    int part = blockIdx.x >> 3;                      // 0..7
    int base = img * PSZ + part * (PSZ / HPART);     // 18432 px per block
#pragma unroll
    for (int it = 0; it < PSZ / HPART / 1024; ++it) {  // 18 iterations
        int n = base + it * 1024 + threadIdx.x;
        float x = pred[n], z = tgt[n];
        float e = errval(x, z);
        if (e > 0.0f) {
            int lab = (z > 0.5f) ? 1 : 0;
            unsigned long long add = (1ull << 46) |
                (unsigned long long)__fmul_rn(e, 16777216.0f);
            atomicAdd(&h[(binof(e) << 1) + lab], add);   // LDS only
        }
    }
    __syncthreads();
    unsigned long long* gh = histp + ((size_t)blockIdx.x << 12);  // [64][4096]
    for (int q = threadIdx.x; q < NBINH * 2; q += 1024) gh[q] = h[q];  // plain store
}

// ---- K3: fused vertical EDT (24-row shared window, 4 px/thread) + elementwise ----
__global__ __launch_bounds__(256) void k_fused(const float* __restrict__ pred,
                                               const float* __restrict__ tgt,
                                               const unsigned int* __restrict__ g2,
                                               float* __restrict__ pB, float* __restrict__ pP,
                                               float* __restrict__ pPT, float* __restrict__ pBnd,
                                               unsigned int* __restrict__ pPc,
                                               unsigned int* __restrict__ maxabsBits) {
    int t = threadIdx.x;
    int img = blockIdx.x & 7;                        // XCD partition: image <-> XCD
    int bb  = blockIdx.x >> 3;                       // 0..143
    int v   = bb * 256 + t;                          // 0..36863
    int j   = v % WW;
    int i0  = (v / WW) * 4;                          // 4 consecutive rows per thread
    const unsigned int* g2i = g2 + (size_t)img * PSZ;
    // 24 independent loads cover the r<=8 window of all 4 pixels (one round trip).
    // Clamped rows only add candidates with larger r^2 -> min stays exact.
    unsigned int w[24];
#pragma unroll
    for (int k = 0; k < 24; ++k) {
        int rr = i0 - 8 + k;
        rr = rr < 0 ? 0 : (rr > HH - 1 ? HH - 1 : rr);
        w[k] = g2i[rr * WW + j];
    }
    float aF[4], aB[4];
#pragma unroll
    for (int m = 0; m < 4; ++m) {
        float f = INF2F, g = INF2F;
#pragma unroll
        for (int k = m; k <= m + 16; ++k) {
            float r2 = d2f(k - 8 - m);
            f = fminf(f, r2 + d2f((int)(w[k] & 0xffffu)));
            g = fminf(g, r2 + d2f((int)(w[k] >> 16)));
        }
        aF[m] = f; aB[m] = g;
    }
    // straggler loop r>8 (exact; essentially never taken on this data)
#pragma unroll
    for (int m = 0; m < 4; ++m) {
        int i = i0 + m;
        for (int r = 9; r < HH; ++r) {
            float r2 = d2f(r);
            if (r2 >= fmaxf(aF[m], aB[m])) break;
            int up = i - r, dn = i + r;
            if (up >= 0) {
                unsigned int ww = g2i[up * WW + j];
                aF[m] = fminf(aF[m], r2 + d2f((int)(ww & 0xffffu)));
                aB[m] = fminf(aB[m], r2 + d2f((int)(ww >> 16)));
            }
            if (dn < HH) {
                unsigned int ww = g2i[dn * WW + j];
                aF[m] = fminf(aF[m], r2 + d2f((int)(ww & 0xffffu)));
                aB[m] = fminf(aB[m], r2 + d2f((int)(ww >> 16)));
            }
        }
    }
    // elementwise for the 4 pixels
    float vals[6] = {0.f, 0.f, 0.f, 0.f, 0.f, 0.f};
#pragma unroll
    for (int m = 0; m < 4; ++m) {
        int n = img * PSZ + (i0 + m) * WW + j;
        float x = pred[n], z = tgt[n];
        bool lab = z > 0.5f;
        float dv = lab ? -sqrtf(fminf(aB[m], INF2F)) : sqrtf(fminf(aF[m], INF2F));
        float bce = fmaxf(x, 0.0f) - x * z + log1pf(expf(-fabsf(x)));
        float p = 1.0f / (1.0f + expf(-x));
        vals[0] += bce; vals[1] += p;
        vals[2] += lab ? p : 0.0f;
        vals[3] += p * dv;
        vals[4] += lab ? 1.0f : 0.0f;
        vals[5] = fmaxf(vals[5], fabsf(dv));
    }
    // wave butterfly reductions (fixed order -> deterministic)
#pragma unroll
    for (int k = 0; k < 5; ++k)
#pragma unroll
        for (int off = 32; off; off >>= 1) vals[k] += __shfl_xor(vals[k], off);
#pragma unroll
    for (int off = 32; off; off >>= 1) vals[5] = fmaxf(vals[5], __shfl_xor(vals[5], off));
    __shared__ float sw[4][6];
    int wv = t >> 6, lnn = t & 63;
    if (lnn == 0) {
#pragma unroll
        for (int k = 0; k < 6; ++k) sw[wv][k] = vals[k];
    }
    __syncthreads();
    if (t < 6) {
        int k = t;
        if (k == 5) {
            float a = fmaxf(fmaxf(sw[0][5], sw[1][5]), fmaxf(sw[2][5], sw[3][5]));
            atomicMax(maxabsBits, __float_as_uint(a));
        } else {
            float a = sw[0][k] + sw[1][k] + sw[2][k] + sw[3][k];
            if (k == 0) pB[blockIdx.x] = a;
            else if (k == 1) pP[blockIdx.x] = a;
            else if (k == 2) pPT[blockIdx.x] = a;
            else if (k == 3) pBnd[blockIdx.x] = a;
            else pPc[blockIdx.x] = (unsigned int)(a + 0.5f);
        }
    }
}

// ---- K4: per-sample Lovasz scan (sums 8 partial hists) + partial-sum reduction ----
__global__ __launch_bounds__(256) void k_scanlov(const unsigned long long* __restrict__ histp,
                                                 const unsigned int* __restrict__ pPc,
                                                 const float* __restrict__ pB, const float* __restrict__ pP,
                                                 const float* __restrict__ pPT, const float* __restrict__ pBnd,
                                                 double* __restrict__ sums,   // [8][5]: B,P,PT,Bnd,Lov
                                                 unsigned int* __restrict__ Pfin) {
    int b = blockIdx.x, t = threadIdx.x;
    __shared__ double dred[256];
    __shared__ unsigned int ured[256];
    // per-sample reduction of the float partials (entries q = b + 8k, k<144)
    double mv[4] = {0.0, 0.0, 0.0, 0.0};
    unsigned int mc = 0;
    if (t < 144) {
        int q = b + 8 * t;
        mv[0] = (double)pB[q]; mv[1] = (double)pP[q];
        mv[2] = (double)pPT[q]; mv[3] = (double)pBnd[q];
        mc = pPc[q];
    }
    ured[t] = mc; __syncthreads();
    for (int s = 128; s > 0; s >>= 1) { if (t < s) ured[t] += ured[t + s]; __syncthreads(); }
    unsigned int Pfull = ured[0];
    __syncthreads();
#pragma unroll
    for (int a = 0; a < 4; ++a) {
        dred[t] = mv[a]; __syncthreads();
        for (int s = 128; s > 0; s >>= 1) { if (t < s) dred[t] += dred[t + s]; __syncthreads(); }
        if (t == 0) sums[b * 5 + a] = dred[0];
        __syncthreads();
    }
    // gather 8 bins/thread, summing the 8 per-image partial histograms
    int m0 = t * 8;
    unsigned int ln = 0, lp = 0;
    unsigned int hcn[8], hcp[8];
    unsigned long long hsn[8], hsp[8];
#pragma unroll
    for (int k = 0; k < 8; ++k) {
        unsigned long long vn = 0ull, vp = 0ull;
#pragma unroll
        for (int pp = 0; pp < HPART; ++pp) {
            const unsigned long long* hc = histp + ((size_t)(pp * 8 + b) << 12);
            vn += hc[2 * (m0 + k)];
            vp += hc[2 * (m0 + k) + 1];
        }
        hcn[k] = (unsigned int)(vn >> 46); hcp[k] = (unsigned int)(vp >> 46);
        hsn[k] = vn & ((1ull << 46) - 1);  hsp[k] = vp & ((1ull << 46) - 1);
        ln += hcn[k]; lp += hcp[k];
    }
    int lane = t & 63, wv = t >> 6;
    unsigned int sln = ln, slp = lp;
#pragma unroll
    for (int off = 1; off < 64; off <<= 1) {
        unsigned int an = __shfl_up(sln, off);
        unsigned int ap = __shfl_up(slp, off);
        if (lane >= off) { sln += an; slp += ap; }
    }
    __shared__ unsigned int wN[4], wP[4];
    if (lane == 63) { wN[wv] = sln; wP[wv] = slp; }
    __syncthreads();
    unsigned int baseN = 0, baseP = 0, totN = 0, totP = 0;
#pragma unroll
    for (int q = 0; q < 4; ++q) {
        if (q < wv) { baseN += wN[q]; baseP += wP[q]; }
        totN += wN[q]; totP += wP[q];
    }
    unsigned int runN = baseN + sln - ln;            // bins < m0
    unsigned int runP = baseP + slp - lp;
    // Lovasz closed form, 2 f64 divisions per nonempty bin
    const double EPS = 1e-7;
    const double SCL = 1.0 / 16777216.0;
    double P = (double)Pfull;
    double l = 0.0;
#pragma unroll
    for (int k = 0; k < 8; ++k) {
        unsigned int hn = hcn[k], hp = hcp[k];
        if (hn | hp) {
            double negAbove = (double)(totN - runN - hn);   // negatives in higher bins
            double D0 = P + negAbove + EPS;
            if (hp) l += ((double)hsp[k] * SCL) / D0;       // bin positives share denom
            if (hn) {
                double pAbove = (double)(totP - runP);      // positives ranked above group
                double D1 = D0 + (double)hn;
                // (P-pAbove)*(sn/hn)*(1/D0-1/D1) == (P-pAbove)*sn/(D0*D1)
                l += (P - pAbove) * ((double)hsn[k] * SCL) / (D0 * D1);
            }
            runN += hn; runP += hp;
        }
    }
    dred[t] = l; __syncthreads();
    for (int s = 128; s > 0; s >>= 1) { if (t < s) dred[t] += dred[t + s]; __syncthreads(); }
    if (t == 0) { sums[b * 5 + 4] = dred[0]; Pfin[b] = Pfull; }
}

// ---- K5: final combine (tiny, deterministic) ----
__global__ __launch_bounds__(64) void k_final(const double* __restrict__ sums,
                                              const unsigned int* __restrict__ Pfin,
                                              const unsigned int* __restrict__ maxabsBits,
                                              float* __restrict__ out) {
    if (threadIdx.x == 0) {
        double sumBCE = 0, sumP = 0, sumPT = 0, sumBD = 0, sumLV = 0, tsum = 0;
        for (int b = 0; b < NIMG; ++b) {
            sumBCE += sums[b * 5 + 0];
            sumP   += sums[b * 5 + 1];
            sumPT  += sums[b * 5 + 2];
            sumBD  += sums[b * 5 + 3];
            sumLV  += sums[b * 5 + 4];
            tsum   += (double)Pfin[b];
        }
        double bce = sumBCE / (double)NTOT;
        double dice = 1.0 - (2.0 * sumPT + 1.0) / (sumP + tsum + 1.0);
        float ma = __uint_as_float(maxabsBits[0]);
        double bnd = sumBD / (double)NTOT;
        if (ma > 0.0f) bnd = bnd / (double)ma;
        double lov = sumLV / (double)NIMG;
        double loss = 0.3 * bce + 0.3 * dice + 0.2 * bnd + 0.2 * lov;
        if (loss < 0.0) loss = 0.0;
        if (loss > 100.0) loss = 100.0;
        out[0] = (float)loss;
    }
}

extern "C" void kernel_launch(void* const* d_in, const int* in_sizes, int n_in,
                              void* d_out, int out_size, void* d_ws, size_t ws_size,
                              hipStream_t stream) {
    const float* pred = (const float*)d_in[0];
    const float* tgt  = (const float*)d_in[1];
    char* ws = (char*)d_ws;

    size_t off = 0;
    unsigned long long* histp = (unsigned long long*)(ws + off);
    off += (size_t)NIMG * HPART * NBINH * 2 * 8;     // 2 MB of per-block partials
    unsigned int* maxabsBits = (unsigned int*)(ws + off); off += 64;
    off = (off + 1023) & ~(size_t)1023;
    double* sums = (double*)(ws + off); off += NIMG * 5 * 8;
    unsigned int* Pfin = (unsigned int*)(ws + off); off += NIMG * 4;
    off = (off + 63) & ~(size_t)63;
    float* pB   = (float*)(ws + off); off += (size_t)GV2 * 4;
    float* pP   = (float*)(ws + off); off += (size_t)GV2 * 4;
    float* pPT  = (float*)(ws + off); off += (size_t)GV2 * 4;
    float* pBnd = (float*)(ws + off); off += (size_t)GV2 * 4;
    unsigned int* pPc = (unsigned int*)(ws + off); off += (size_t)GV2 * 4;
    off = (off + 1023) & ~(size_t)1023;
    unsigned int* g2 = (unsigned int*)(ws + off); off += (size_t)NIMG * PSZ * 4;
    (void)off; (void)ws_size; (void)in_sizes; (void)n_in; (void)out_size;

    k_edth<<<EBLK, 256, 0, stream>>>(tgt, g2, maxabsBits);
    k_hist<<<NIMG * HPART, 1024, 0, stream>>>(pred, tgt, histp);
    k_fused<<<GV2, 256, 0, stream>>>(pred, tgt, g2, pB, pP, pPT, pBnd, pPc, maxabsBits);
    k_scanlov<<<NIMG, 256, 0, stream>>>(histp, pPc, pB, pP, pPT, pBnd, sums, Pfin);
    k_final<<<1, 64, 0, stream>>>(sums, Pfin, maxabsBits, (float*)d_out);
}